// Round 1
// baseline (2233.966 us; speedup 1.0000x reference)
//
#include <hip/hip_runtime.h>
#include <stdint.h>

#define DIMN 1024
#define TSTEPS 2048
#define BATCH 16
#define MTOT (TSTEPS*BATCH)   // 32768
#define CH (BATCH*DIMN)       // 16384 channels

typedef unsigned short u16;
typedef __attribute__((ext_vector_type(8))) __bf16 bf16x8;
typedef __attribute__((ext_vector_type(4))) float floatx4;

__device__ __forceinline__ float bf2f(u16 u) {
    unsigned v = ((unsigned)u) << 16;
    return __builtin_bit_cast(float, v);
}
__device__ __forceinline__ u16 f2bf(float f) {
    __bf16 b = (__bf16)f;   // RNE convert
    return __builtin_bit_cast(u16, b);
}
__device__ __forceinline__ float tanh_fast(float x) {
    // 1 - 2/(exp(2x)+1); saturates correctly at +/-1 for large |x|
    float e = __expf(2.f * x);
    return 1.f - 2.f / (e + 1.f);
}
__device__ __forceinline__ void gl_lds16(const void* g, void* l) {
    // async global->LDS, 16B per lane; LDS dest must be wave-uniform base + lane*16
    __builtin_amdgcn_global_load_lds(
        (const __attribute__((address_space(1))) void*)g,
        (__attribute__((address_space(3))) void*)l,
        16, 0, 0);
}

// -------- f32 -> bf16 conversion (x and weights) --------
__global__ void cvt_kernel(const float* __restrict__ src, u16* __restrict__ dst, int n4) {
    int i = blockIdx.x * blockDim.x + threadIdx.x;
    if (i >= n4) return;
    float4 v = ((const float4*)src)[i];
    ushort4 o;
    o.x = f2bf(v.x); o.y = f2bf(v.y); o.z = f2bf(v.z); o.w = f2bf(v.w);
    ((ushort4*)dst)[i] = o;
}

// -------- unified 128x128 MFMA GEMM: C = A(bf16) * W(bf16)^T, epilogue by mode --------
// mode 0: outB = bf16(sigmoid(acc + bias))          (delta)
// mode 1: outB = bf16(acc + bias)                   (cand_in)
// mode 2: outF = bf16(cmp) * silu(acc)              (outs, f32)
__global__ __launch_bounds__(256) void gemm_bt(
    const u16* __restrict__ A, const u16* __restrict__ W,
    const float* __restrict__ bias,
    u16* __restrict__ outB, float* __restrict__ outF,
    const u16* __restrict__ cmp, int mode)
{
    __shared__ alignas(16) u16 a_sh[128 * 32];
    __shared__ alignas(16) u16 b_sh[128 * 32];
    const int tid  = threadIdx.x;
    const int lane = tid & 63;
    const int wave = tid >> 6;
    const int wm = wave & 1, wn = wave >> 1;
    const int m0 = blockIdx.x * 128, n0 = blockIdx.y * 128;
    const int row = lane & 15, quad = lane >> 4;

    // staging: thread t loads 16B chunk (row = t>>2, kchunk = t&3); two rounds for 128 rows
    const u16* Ag0 = A + (size_t)(m0 + (tid >> 2)) * DIMN + (tid & 3) * 8;
    const u16* Ag1 = Ag0 + (size_t)64 * DIMN;
    const u16* Wg0 = W + (size_t)(n0 + (tid >> 2)) * DIMN + (tid & 3) * 8;
    const u16* Wg1 = Wg0 + (size_t)64 * DIMN;
    u16* a_d0 = a_sh + tid * 8; u16* a_d1 = a_sh + 2048 + tid * 8;
    u16* b_d0 = b_sh + tid * 8; u16* b_d1 = b_sh + 2048 + tid * 8;

    floatx4 acc[4][4];
    #pragma unroll
    for (int i = 0; i < 4; i++)
        #pragma unroll
        for (int j = 0; j < 4; j++) acc[i][j] = (floatx4)(0.0f);

    int aoff[4], boff[4];
    #pragma unroll
    for (int i = 0; i < 4; i++) aoff[i] = (wm * 64 + i * 16 + row) * 32 + quad * 8;
    #pragma unroll
    for (int j = 0; j < 4; j++) boff[j] = (wn * 64 + j * 16 + row) * 32 + quad * 8;

    for (int kt = 0; kt < DIMN; kt += 32) {
        __syncthreads();                 // previous compute done with LDS
        gl_lds16(Ag0 + kt, a_d0);
        gl_lds16(Ag1 + kt, a_d1);
        gl_lds16(Wg0 + kt, b_d0);
        gl_lds16(Wg1 + kt, b_d1);
        __syncthreads();                 // drains vmcnt -> LDS tiles ready
        bf16x8 av[4], bv[4];
        #pragma unroll
        for (int i = 0; i < 4; i++) av[i] = *(const bf16x8*)(a_sh + aoff[i]);
        #pragma unroll
        for (int j = 0; j < 4; j++) bv[j] = *(const bf16x8*)(b_sh + boff[j]);
        #pragma unroll
        for (int i = 0; i < 4; i++)
            #pragma unroll
            for (int j = 0; j < 4; j++)
                acc[i][j] = __builtin_amdgcn_mfma_f32_16x16x32_bf16(av[i], bv[j], acc[i][j], 0, 0, 0);
    }

    // C/D mapping (verified): col = lane&15, row = quad*4 + reg
    const int mb = m0 + wm * 64 + quad * 4;
    const int nb = n0 + wn * 64 + row;
    if (mode == 2) {
        #pragma unroll
        for (int i = 0; i < 4; i++)
            #pragma unroll
            for (int j = 0; j < 4; j++)
                #pragma unroll
                for (int r = 0; r < 4; r++) {
                    size_t idx = (size_t)(mb + i * 16 + r) * DIMN + (nb + j * 16);
                    float z = acc[i][j][r];
                    float sil = z / (1.f + __expf(-z));
                    outF[idx] = bf2f(cmp[idx]) * sil;
                }
    } else if (mode == 0) {
        #pragma unroll
        for (int i = 0; i < 4; i++)
            #pragma unroll
            for (int j = 0; j < 4; j++)
                #pragma unroll
                for (int r = 0; r < 4; r++) {
                    int n = nb + j * 16;
                    float v = acc[i][j][r] + bias[n];
                    v = 1.f / (1.f + __expf(-v));
                    outB[(size_t)(mb + i * 16 + r) * DIMN + n] = f2bf(v);
                }
    } else {
        #pragma unroll
        for (int i = 0; i < 4; i++)
            #pragma unroll
            for (int j = 0; j < 4; j++)
                #pragma unroll
                for (int r = 0; r < 4; r++) {
                    int n = nb + j * 16;
                    float v = acc[i][j][r] + bias[n];
                    outB[(size_t)(mb + i * 16 + r) * DIMN + n] = f2bf(v);
                }
    }
}

// -------- diagonal scan: 16384 channels, sequential over T; fused group-softmax --------
#define PF 16
__global__ __launch_bounds__(64) void scan_kernel(
    const u16* __restrict__ dB, const u16* __restrict__ cB,
    const float* __restrict__ h0, const float* __restrict__ r_h,
    float* __restrict__ hAll, u16* __restrict__ hB, u16* __restrict__ cmp)
{
    const int c = blockIdx.x * 64 + threadIdx.x;   // channel = b*1024 + d
    const int d = c & (DIMN - 1);
    float h = h0[c];
    const float r = r_h[d];
    hAll[c] = h;                                   // h_all[0] = h0

    u16 dR[PF], cR[PF];
    #pragma unroll
    for (int i = 0; i < PF; i++) {
        dR[i] = dB[(size_t)i * CH + c];
        cR[i] = cB[(size_t)i * CH + c];
    }

    for (int tb = 0; tb < TSTEPS; tb += PF) {
        #pragma unroll
        for (int i = 0; i < PF; i++) {
            const int t = tb + i;
            float dlt = bf2f(dR[i]);
            float cin = bf2f(cR[i]);
            if (t + PF < TSTEPS) {                 // prefetch ring
                dR[i] = dB[(size_t)(t + PF) * CH + c];
                cR[i] = cB[(size_t)(t + PF) * CH + c];
            }
            float cand = tanh_fast(fmaf(r, h, cin));
            h = fmaf(dlt, cand - h, h);            // (1-d)h + d*cand

            // softmax over the 32-lane group (lanes 0-31 / 32-63 are separate groups)
            float mx = h;
            #pragma unroll
            for (int s = 16; s > 0; s >>= 1) mx = fmaxf(mx, __shfl_xor(mx, s));
            float e = __expf(h - mx);
            float sum = e;
            #pragma unroll
            for (int s = 16; s > 0; s >>= 1) sum += __shfl_xor(sum, s);
            float cp = e / sum;

            size_t base = (size_t)t * CH + c;
            hAll[base + CH] = h;
            hB[base] = f2bf(h);
            cmp[base] = f2bf(cp);
        }
    }
}

extern "C" void kernel_launch(void* const* d_in, const int* in_sizes, int n_in,
                              void* d_out, int out_size, void* d_ws, size_t ws_size,
                              hipStream_t stream) {
    const float* x   = (const float*)d_in[0];
    const float* h0  = (const float*)d_in[1];
    const float* W_x = (const float*)d_in[2];
    const float* r_h = (const float*)d_in[3];
    const float* b   = (const float*)d_in[4];
    const float* W_d = (const float*)d_in[5];
    const float* b_d = (const float*)d_in[6];
    const float* W_o = (const float*)d_in[7];
    float* out = (float*)d_out;

    char* ws = (char*)d_ws;
    // layout (bytes): xb 64MB | wdB 2MB | wxB 2MB | woB 2MB | dBuf 64MB | cBuf 64MB | cmpB 64MB
    u16* xb   = (u16*)(ws);
    u16* wdB  = (u16*)(ws + 67108864);
    u16* wxB  = (u16*)(ws + 69206016);
    u16* woB  = (u16*)(ws + 71303168);
    u16* dBuf = (u16*)(ws + 73400320);
    u16* cBuf = (u16*)(ws + 140509184);
    u16* cmpB = (u16*)(ws + 207618048);
    u16* hB   = xb;   // xb dead after the two pre-GEMMs; scan reuses it for bf16 h

    cvt_kernel<<<dim3(33554432 / 4 / 256), 256, 0, stream>>>(x, xb, 33554432 / 4);
    cvt_kernel<<<dim3(1048576 / 4 / 256), 256, 0, stream>>>(W_d, wdB, 1048576 / 4);
    cvt_kernel<<<dim3(1048576 / 4 / 256), 256, 0, stream>>>(W_x, wxB, 1048576 / 4);
    cvt_kernel<<<dim3(1048576 / 4 / 256), 256, 0, stream>>>(W_o, woB, 1048576 / 4);

    dim3 g(MTOT / 128, DIMN / 128);   // 256 x 8
    gemm_bt<<<g, 256, 0, stream>>>(xb, wdB, b_d, dBuf, nullptr, nullptr, 0);
    gemm_bt<<<g, 256, 0, stream>>>(xb, wxB, b,   cBuf, nullptr, nullptr, 1);
    scan_kernel<<<256, 64, 0, stream>>>(dBuf, cBuf, h0, r_h, out, hB, cmpB);
    gemm_bt<<<g, 256, 0, stream>>>(hB, woB, nullptr, nullptr, out + 33570816, cmpB, 2);
}

// Round 2
// 1543.577 us; speedup vs baseline: 1.4473x; 1.4473x over previous
//
#include <hip/hip_runtime.h>
#include <stdint.h>

#define DIMN 1024
#define TSTEPS 2048
#define BATCH 16
#define MTOT (TSTEPS*BATCH)   // 32768
#define CH (BATCH*DIMN)       // 16384 channels

typedef unsigned short u16;
typedef __attribute__((ext_vector_type(8))) __bf16 bf16x8;
typedef __attribute__((ext_vector_type(4))) float floatx4;

__device__ __forceinline__ float bf2f(u16 u) {
    unsigned v = ((unsigned)u) << 16;
    return __builtin_bit_cast(float, v);
}
__device__ __forceinline__ u16 f2bf(float f) {
    __bf16 b = (__bf16)f;   // RNE convert
    return __builtin_bit_cast(u16, b);
}
__device__ __forceinline__ float tanh_fast(float x) {
    float e = __expf(2.f * x);
    return 1.f - 2.f / (e + 1.f);
}
__device__ __forceinline__ void gl_lds16(const void* g, void* l) {
    __builtin_amdgcn_global_load_lds(
        (const __attribute__((address_space(1))) void*)g,
        (__attribute__((address_space(3))) void*)l,
        16, 0, 0);
}

// -------- f32 -> bf16 conversion (x and weights) --------
__global__ void cvt_kernel(const float* __restrict__ src, u16* __restrict__ dst, int n4) {
    int i = blockIdx.x * blockDim.x + threadIdx.x;
    if (i >= n4) return;
    float4 v = ((const float4*)src)[i];
    ushort4 o;
    o.x = f2bf(v.x); o.y = f2bf(v.y); o.z = f2bf(v.z); o.w = f2bf(v.w);
    ((ushort4*)dst)[i] = o;
}

// -------- unified 128x128 MFMA GEMM: C = A(bf16) * W(bf16)^T, epilogue by mode --------
__global__ __launch_bounds__(256) void gemm_bt(
    const u16* __restrict__ A, const u16* __restrict__ W,
    const float* __restrict__ bias,
    u16* __restrict__ outB, float* __restrict__ outF,
    const u16* __restrict__ cmp, int mode)
{
    __shared__ alignas(16) u16 a_sh[128 * 32];
    __shared__ alignas(16) u16 b_sh[128 * 32];
    const int tid  = threadIdx.x;
    const int lane = tid & 63;
    const int wave = tid >> 6;
    const int wm = wave & 1, wn = wave >> 1;
    const int m0 = blockIdx.x * 128, n0 = blockIdx.y * 128;
    const int row = lane & 15, quad = lane >> 4;

    const u16* Ag0 = A + (size_t)(m0 + (tid >> 2)) * DIMN + (tid & 3) * 8;
    const u16* Ag1 = Ag0 + (size_t)64 * DIMN;
    const u16* Wg0 = W + (size_t)(n0 + (tid >> 2)) * DIMN + (tid & 3) * 8;
    const u16* Wg1 = Wg0 + (size_t)64 * DIMN;
    u16* a_d0 = a_sh + tid * 8; u16* a_d1 = a_sh + 2048 + tid * 8;
    u16* b_d0 = b_sh + tid * 8; u16* b_d1 = b_sh + 2048 + tid * 8;

    floatx4 acc[4][4];
    #pragma unroll
    for (int i = 0; i < 4; i++)
        #pragma unroll
        for (int j = 0; j < 4; j++) acc[i][j] = (floatx4)(0.0f);

    int aoff[4], boff[4];
    #pragma unroll
    for (int i = 0; i < 4; i++) aoff[i] = (wm * 64 + i * 16 + row) * 32 + quad * 8;
    #pragma unroll
    for (int j = 0; j < 4; j++) boff[j] = (wn * 64 + j * 16 + row) * 32 + quad * 8;

    for (int kt = 0; kt < DIMN; kt += 32) {
        __syncthreads();
        gl_lds16(Ag0 + kt, a_d0);
        gl_lds16(Ag1 + kt, a_d1);
        gl_lds16(Wg0 + kt, b_d0);
        gl_lds16(Wg1 + kt, b_d1);
        __syncthreads();
        bf16x8 av[4], bv[4];
        #pragma unroll
        for (int i = 0; i < 4; i++) av[i] = *(const bf16x8*)(a_sh + aoff[i]);
        #pragma unroll
        for (int j = 0; j < 4; j++) bv[j] = *(const bf16x8*)(b_sh + boff[j]);
        #pragma unroll
        for (int i = 0; i < 4; i++)
            #pragma unroll
            for (int j = 0; j < 4; j++)
                acc[i][j] = __builtin_amdgcn_mfma_f32_16x16x32_bf16(av[i], bv[j], acc[i][j], 0, 0, 0);
    }

    // C/D mapping: col = lane&15, row = quad*4 + reg
    const int mb = m0 + wm * 64 + quad * 4;
    const int nb = n0 + wn * 64 + row;
    if (mode == 2) {
        #pragma unroll
        for (int i = 0; i < 4; i++)
            #pragma unroll
            for (int j = 0; j < 4; j++)
                #pragma unroll
                for (int r = 0; r < 4; r++) {
                    size_t idx = (size_t)(mb + i * 16 + r) * DIMN + (nb + j * 16);
                    float z = acc[i][j][r];
                    float sil = z / (1.f + __expf(-z));
                    outF[idx] = bf2f(cmp[idx]) * sil;
                }
    } else if (mode == 0) {
        #pragma unroll
        for (int i = 0; i < 4; i++)
            #pragma unroll
            for (int j = 0; j < 4; j++)
                #pragma unroll
                for (int r = 0; r < 4; r++) {
                    int n = nb + j * 16;
                    float v = acc[i][j][r] + bias[n];
                    v = 1.f / (1.f + __expf(-v));
                    outB[(size_t)(mb + i * 16 + r) * DIMN + n] = f2bf(v);
                }
    } else {
        #pragma unroll
        for (int i = 0; i < 4; i++)
            #pragma unroll
            for (int j = 0; j < 4; j++)
                #pragma unroll
                for (int r = 0; r < 4; r++) {
                    int n = nb + j * 16;
                    float v = acc[i][j][r] + bias[n];
                    outB[(size_t)(mb + i * 16 + r) * DIMN + n] = f2bf(v);
                }
    }
}

// -------- diagonal scan: h only, minimal dependent chain --------
#define PF 32
__global__ __launch_bounds__(64) void scan_kernel(
    const u16* __restrict__ dB, const u16* __restrict__ cB,
    const float* __restrict__ h0, const float* __restrict__ r_h,
    float* __restrict__ hAll)
{
    const int c = blockIdx.x * 64 + threadIdx.x;   // channel = b*1024 + d
    const int d = c & (DIMN - 1);
    float h = h0[c];
    const float r = r_h[d];
    hAll[c] = h;                                   // h_all[0] = h0

    u16 dR[PF], cR[PF];
    #pragma unroll
    for (int i = 0; i < PF; i++) {
        dR[i] = dB[(size_t)i * CH + c];
        cR[i] = cB[(size_t)i * CH + c];
    }

    for (int tb = 0; tb < TSTEPS; tb += PF) {
        #pragma unroll
        for (int i = 0; i < PF; i++) {
            const int t = tb + i;
            float dlt = bf2f(dR[i]);
            float cin = bf2f(cR[i]);
            if (t + PF < TSTEPS) {                 // prefetch ring
                dR[i] = dB[(size_t)(t + PF) * CH + c];
                cR[i] = cB[(size_t)(t + PF) * CH + c];
            }
            float cand = tanh_fast(fmaf(r, h, cin));
            h = fmaf(dlt, cand - h, h);            // (1-d)h + d*cand
            hAll[(size_t)(t + 1) * CH + c] = h;
        }
    }
}

// -------- parallel group-softmax + bf16 cast of h (post-scan, BW-bound) --------
// one thread = 4 channels (float4); 8 threads = one 32-wide softmax group
__global__ __launch_bounds__(256) void post_kernel(
    const float* __restrict__ hAll, u16* __restrict__ hB, u16* __restrict__ cmp)
{
    const int gid = blockIdx.x * 256 + threadIdx.x;     // over T*CH/4
    float4 hv = ((const float4*)(hAll + CH))[gid];

    float m = fmaxf(fmaxf(hv.x, hv.y), fmaxf(hv.z, hv.w));
    #pragma unroll
    for (int s = 4; s > 0; s >>= 1) m = fmaxf(m, __shfl_xor(m, s));
    float ex = __expf(hv.x - m), ey = __expf(hv.y - m);
    float ez = __expf(hv.z - m), ew = __expf(hv.w - m);
    float sum = ex + ey + ez + ew;
    #pragma unroll
    for (int s = 4; s > 0; s >>= 1) sum += __shfl_xor(sum, s);
    float inv = 1.f / sum;

    ushort4 co, ho;
    co.x = f2bf(ex * inv); co.y = f2bf(ey * inv);
    co.z = f2bf(ez * inv); co.w = f2bf(ew * inv);
    ho.x = f2bf(hv.x); ho.y = f2bf(hv.y); ho.z = f2bf(hv.z); ho.w = f2bf(hv.w);
    ((ushort4*)cmp)[gid] = co;
    ((ushort4*)hB)[gid] = ho;
}

extern "C" void kernel_launch(void* const* d_in, const int* in_sizes, int n_in,
                              void* d_out, int out_size, void* d_ws, size_t ws_size,
                              hipStream_t stream) {
    const float* x   = (const float*)d_in[0];
    const float* h0  = (const float*)d_in[1];
    const float* W_x = (const float*)d_in[2];
    const float* r_h = (const float*)d_in[3];
    const float* b   = (const float*)d_in[4];
    const float* W_d = (const float*)d_in[5];
    const float* b_d = (const float*)d_in[6];
    const float* W_o = (const float*)d_in[7];
    float* out = (float*)d_out;

    char* ws = (char*)d_ws;
    u16* xb   = (u16*)(ws);
    u16* wdB  = (u16*)(ws + 67108864);
    u16* wxB  = (u16*)(ws + 69206016);
    u16* woB  = (u16*)(ws + 71303168);
    u16* dBuf = (u16*)(ws + 73400320);
    u16* cBuf = (u16*)(ws + 140509184);
    u16* cmpB = (u16*)(ws + 207618048);
    u16* hB   = xb;   // xb dead after the two pre-GEMMs

    cvt_kernel<<<dim3(33554432 / 4 / 256), 256, 0, stream>>>(x, xb, 33554432 / 4);
    cvt_kernel<<<dim3(1048576 / 4 / 256), 256, 0, stream>>>(W_d, wdB, 1048576 / 4);
    cvt_kernel<<<dim3(1048576 / 4 / 256), 256, 0, stream>>>(W_x, wxB, 1048576 / 4);
    cvt_kernel<<<dim3(1048576 / 4 / 256), 256, 0, stream>>>(W_o, woB, 1048576 / 4);

    dim3 g(MTOT / 128, DIMN / 128);   // 256 x 8
    gemm_bt<<<g, 256, 0, stream>>>(xb, wdB, b_d, dBuf, nullptr, nullptr, 0);
    gemm_bt<<<g, 256, 0, stream>>>(xb, wxB, b,   cBuf, nullptr, nullptr, 1);
    scan_kernel<<<256, 64, 0, stream>>>(dBuf, cBuf, h0, r_h, out);
    post_kernel<<<dim3(TSTEPS * CH / 4 / 256), 256, 0, stream>>>(out, hB, cmpB);
    gemm_bt<<<g, 256, 0, stream>>>(hB, woB, nullptr, nullptr, out + 33570816, cmpB, 2);
}